// Round 11
// baseline (8851.402 us; speedup 1.0000x reference)
//
#include <hip/hip_runtime.h>
#include <hip/hip_bf16.h>

// ---------------------------------------------------------------------------
// CCAMemoryModel forward, f32 throughout.
//  k_proj2 : per-image tiled GEMM proj (mean-shift+BN+ReLU+L2norm);
//            block 72 composes Winograd K1w in [tap][c][4] layout
//            (one float4 = 4 Winograd coeffs of channel c at tap).
//  k_corr  : per (b,n) 100x100x64 GEMM -> corr[bn][m][bpos].
//  k_cca   : 2 waves/block, wave = (wm, bn, mr-half) strip (round-8 body).
//            K1w + w2a staged in LDS: weight reads become uniform-address
//            ds_read_b128 with compile-time offsets (kills ~1300 VMEM
//            loads + ~2600 addr-VALU per mr that dominated VALUBusy).
//  k_msoft2: fused g2 mem-conv (w2b) + gaussian-normalize + softmax over mem
//            + sum over base -> attn_memory.
//  k_attmem: att_mem[b,n,c]
//  k_final : enc + cosine weights (parallelized over 512 thr) + softmax +
//            mem_vec + linear head
// ---------------------------------------------------------------------------

// Blocks 0..71: proj per image. Block 72: Winograd filter transform K1w.
__global__ __launch_bounds__(512) void k_proj2(const float* __restrict__ feat_b,
                                               const float* __restrict__ feat_m,
                                               const float* __restrict__ w1x1,
                                               const float* __restrict__ gamma,
                                               const float* __restrict__ beta,
                                               const float* __restrict__ w1a,
                                               const float* __restrict__ w1b,
                                               float* __restrict__ K1w,
                                               float* __restrict__ fbp,
                                               float* __restrict__ fmp) {
    __shared__ __align__(16) float xt[64][104];   // c-tile of x; reused as zbuf
    __shared__ __align__(16) float wt[64][68];    // c-tile of w1x1
    __shared__ float colsum[100];
    __shared__ float wsumL[64];
    __shared__ float invL[100];
    const int tid = threadIdx.x;
    const int img = blockIdx.x;
    if (img == 72) {
        // K1w[tap*64 + c*4 + j], tap = (dmh*3+dmw)*3+dbh, j = Winograd coeff.
        for (int t = tid; t < 432; t += 512) {
            int tap = t >> 4, c = t & 15;
            int dm = tap / 3, dbh = tap % 3;
            float g0 = 0.f, g1 = 0.f, g2 = 0.f;
            for (int cp = 0; cp < 16; ++cp) {
                float wb = w1b[(c * 16 + cp) * 9 + dm];
                g0 = fmaf(wb, w1a[cp * 9 + dbh * 3 + 0], g0);
                g1 = fmaf(wb, w1a[cp * 9 + dbh * 3 + 1], g1);
                g2 = fmaf(wb, w1a[cp * 9 + dbh * 3 + 2], g2);
            }
            int base = tap * 64 + c * 4;
            K1w[base + 0] = g0;
            K1w[base + 1] = 0.5f * (g0 + g1 + g2);
            K1w[base + 2] = 0.5f * (g0 - g1 + g2);
            K1w[base + 3] = g2;
        }
        return;
    }
    const float* x;
    float* outp;
    if (img < 8) { x = feat_b + (size_t)img * 51200; outp = fbp + (size_t)img * 6400; }
    else         { x = feat_m + (size_t)(img - 8) * 51200; outp = fmp + (size_t)(img - 8) * 6400; }

    if (tid < 100) colsum[tid] = 0.f;
    if (tid < 64) wsumL[tid] = 0.f;
    const int r = tid >> 3, q = tid & 7;   // r: out-channel, q: hw-strip
    float acc[13];
#pragma unroll
    for (int j = 0; j < 13; ++j) acc[j] = 0.f;
    __syncthreads();

    for (int ct = 0; ct < 8; ++ct) {
        for (int i = tid; i < 1600; i += 512) {
            int row = i / 25, c4 = (i % 25) * 4;
            *(float4*)&xt[row][c4] = *(const float4*)&x[(size_t)(ct * 64 + row) * 100 + c4];
        }
        for (int i = tid; i < 1024; i += 512) {
            int row = i / 16, c4 = (i % 16) * 4;
            *(float4*)&wt[row][c4] = *(const float4*)&w1x1[(size_t)row * 512 + ct * 64 + c4];
        }
        __syncthreads();
        if (tid < 100) {
            float s = 0.f;
            for (int c = 0; c < 64; ++c) s += xt[c][tid];
            colsum[tid] += s;
        }
        if (tid < 64) {
            float s = 0.f;
            for (int c = 0; c < 64; ++c) s += wt[tid][c];
            wsumL[tid] += s;
        }
        for (int c = 0; c < 64; ++c) {
            float w = wt[r][c];
#pragma unroll
            for (int j = 0; j < 13; ++j) {
                int hw = q + 8 * j;
                if (hw < 100) acc[j] = fmaf(w, xt[c][hw], acc[j]);
            }
        }
        __syncthreads();
    }
    float g = gamma[r], be = beta[r], wsr = wsumL[r];
#pragma unroll
    for (int j = 0; j < 13; ++j) {
        int hw = q + 8 * j;
        if (hw < 100) {
            float mean = colsum[hw] * (1.f / 512.f);
            xt[r][hw] = fmaxf((acc[j] - mean * wsr) * g + be, 0.f);
        }
    }
    __syncthreads();
    if (tid < 100) {
        float ss = 0.f;
        for (int rr = 0; rr < 64; ++rr) { float z = xt[rr][tid]; ss = fmaf(z, z, ss); }
        invL[tid] = 1.f / fmaxf(sqrtf(ss), 1e-8f);
    }
    __syncthreads();
    for (int i = tid; i < 6400; i += 512) {
        int rr = i / 100, hw = i % 100;
        outp[i] = xt[rr][hw] * invL[hw];
    }
}

// corr[bn][m][b] = sum_r fm[r][m]*fb[r][b]. 512 blocks.
__global__ __launch_bounds__(512) void k_corr(const float* __restrict__ fbp,
                                              const float* __restrict__ fmp,
                                              float* __restrict__ corr) {
    __shared__ __align__(16) float A[6400];
    __shared__ __align__(16) float B[6400];
    const int tid = threadIdx.x, bn = blockIdx.x;
    const float* fm = fmp + (size_t)(bn & 63) * 6400;
    const float* fb = fbp + (size_t)(bn >> 6) * 6400;
    for (int i = tid * 4; i < 6400; i += 2048) {
        *(float4*)&A[i] = *(const float4*)&fm[i];
        *(float4*)&B[i] = *(const float4*)&fb[i];
    }
    __syncthreads();
    float* dst = corr + (size_t)bn * 10000;
    for (int u = tid; u < 625; u += 512) {
        int m0 = (u / 25) * 4, b0 = (u % 25) * 4;
        float acc[4][4] = {};
        for (int r = 0; r < 64; ++r) {
            float4 av = *(const float4*)&A[r * 100 + m0];
            float4 bv = *(const float4*)&B[r * 100 + b0];
            float a[4] = {av.x, av.y, av.z, av.w};
            float bb[4] = {bv.x, bv.y, bv.z, bv.w};
#pragma unroll
            for (int i = 0; i < 4; ++i)
#pragma unroll
                for (int j = 0; j < 4; ++j) acc[i][j] = fmaf(a[i], bb[j], acc[i][j]);
        }
#pragma unroll
        for (int i = 0; i < 4; ++i)
#pragma unroll
            for (int j = 0; j < 4; ++j) dst[(m0 + i) * 100 + (b0 + j)] = acc[i][j];
    }
}

// 2 waves/block, wave = (wm, bn = 2*by+wv, half). grid (10, 256, 2), block 128.
// Per-wave ring: 3 slots x [3 mcols][12 rows][14 cols]; shared zero slab;
// K1s (1728 f32, [tap][c][4]) and w2s (144 f32) staged in LDS so all weight
// reads are uniform-address ds_read with compile-time offsets.
__global__ __launch_bounds__(128, 4) void k_cca(const float* __restrict__ corr,
                                                const float* __restrict__ K1w,
                                                const float* __restrict__ w2a,
                                                float* __restrict__ g1out) {
    __shared__ __align__(16) float ringAll[2][1512];
    __shared__ __align__(16) float zslab[168];
    __shared__ __align__(16) float K1s[1728];
    __shared__ __align__(16) float w2s[144];
    const int tid = threadIdx.x;
    const int lane = tid & 63;
    const int wv = tid >> 6;
    const int wm = blockIdx.x;
    const int bn = blockIdx.y * 2 + wv;
    const int half = blockIdx.z;
    const int mr_lo = half * 5;
    const int Rmax = half ? 9 : 5;
    float* ring = ringAll[wv];

    for (int i = lane; i < 1512; i += 64) ring[i] = 0.f;
    for (int i = tid; i < 168; i += 128) zslab[i] = 0.f;
    for (int i = tid * 4; i < 1728; i += 512) *(float4*)&K1s[i] = *(const float4*)&K1w[i];
    for (int i = tid; i < 144; i += 128) w2s[i] = w2a[i];

    const int u = lane < 50 ? lane : 49;   // clamp spare lanes
    const int bh = u / 5, p = u % 5, bw0 = 2 * p;
    const bool act = lane < 50;

    const float* cbase = corr + (size_t)bn * 10000 + (wm - 1) * 100;
    const int i0 = (wm == 0) ? 100 : 0;
    const int i1 = (wm == 9) ? 200 : 300;

    auto prefetch = [&](int R) {
        const float* src = cbase + R * 1000;
        float* dslot = &ring[(R % 3) * 504];
#pragma unroll
        for (int k = 0; k < 5; ++k) {
            int i = lane + k * 64;
            if (i >= i0 && i < i1) {
                int mc = i / 100, t = i % 100;
                dslot[mc * 168 + (t / 10 + 1) * 14 + (t % 10 + 1)] = src[i];
            }
        }
    };
    __syncthreads();   // zslab/K1s/w2s staged (written by both waves)

    if (mr_lo > 0) prefetch(mr_lo - 1);
    prefetch(mr_lo);

    const int rbase = bh * 14 + bw0;
#pragma unroll
    for (int j = 0; j < 5; ++j) {
        const int mr = mr_lo + j;
        if (mr + 1 <= Rmax) prefetch(mr + 1);   // slot (mr+1)%3: row mr-2, dead

        // ---- h pass: Winograd F(2,3) over bw, 4 accumulator banks ----
        float A1[16], A2[16], A3[16], A4[16];
#pragma unroll
        for (int c = 0; c < 16; ++c) { A1[c] = 0.f; A2[c] = 0.f; A3[c] = 0.f; A4[c] = 0.f; }
        for (int dmh = 0; dmh < 3; ++dmh) {
            int mrow = mr + dmh - 1;
            if ((unsigned)mrow >= 10u) continue;
            const float* slab0 = &ring[(mrow % 3) * 504];
#pragma unroll
            for (int dmw = 0; dmw < 3; ++dmw) {
                bool mv = (unsigned)(wm + dmw - 1) < 10u;
                const float* cb = (mv ? slab0 + dmw * 168 : zslab) + rbase;
                const float* kp = K1s + (dmh * 3 + dmw) * 192;
#pragma unroll
                for (int dbh = 0; dbh < 3; ++dbh) {
                    float2 lo = *(const float2*)&cb[dbh * 14];
                    float2 hi = *(const float2*)&cb[dbh * 14 + 2];
                    float t1 = lo.x - hi.x;
                    float t2 = lo.y + hi.x;
                    float t3 = hi.x - lo.y;
                    float t4 = lo.y - hi.y;
                    const float* kq = kp + dbh * 64;
#pragma unroll
                    for (int c = 0; c < 16; ++c) {
                        float4 kv = *(const float4*)&kq[c * 4];
                        A1[c] = fmaf(t1, kv.x, A1[c]);
                        A2[c] = fmaf(t2, kv.y, A2[c]);
                        A3[c] = fmaf(t3, kv.z, A3[c]);
                        A4[c] = fmaf(t4, kv.w, A4[c]);
                    }
                }
            }
        }

        // ---- g1 base-conv via in-wave shuffles (partial row sums) ----
        float P00 = 0.f, P01 = 0.f, P10 = 0.f, P11 = 0.f, P20 = 0.f, P21 = 0.f;
#pragma unroll
        for (int c = 0; c < 16; ++c) {
            float rr0 = fmaxf(A1[c] + A2[c] + A3[c], 0.f);
            float rr1 = fmaxf(A2[c] - A3[c] - A4[c], 0.f);
            float lA = __shfl(rr1, lane - 1); lA = (p > 0) ? lA : 0.f;   // col bw0-1
            float rA = __shfl(rr0, lane + 1); rA = (p < 4) ? rA : 0.f;   // col bw0+2
            const float* wq = w2s + c * 9;
            P00 = fmaf(wq[0], lA, fmaf(wq[1], rr0, fmaf(wq[2], rr1, P00)));
            P01 = fmaf(wq[0], rr0, fmaf(wq[1], rr1, fmaf(wq[2], rA, P01)));
            P10 = fmaf(wq[3], lA, fmaf(wq[4], rr0, fmaf(wq[5], rr1, P10)));
            P11 = fmaf(wq[3], rr0, fmaf(wq[4], rr1, fmaf(wq[5], rA, P11)));
            P20 = fmaf(wq[6], lA, fmaf(wq[7], rr0, fmaf(wq[8], rr1, P20)));
            P21 = fmaf(wq[6], rr0, fmaf(wq[7], rr1, fmaf(wq[8], rA, P21)));
        }
        // out row bh takes: P0 from row bh-1 (lane-5), own P1, P2 from row bh+1.
        float u00 = __shfl(P00, lane - 5), u01 = __shfl(P01, lane - 5);
        float u20 = __shfl(P20, lane + 5), u21 = __shfl(P21, lane + 5);
        if (bh == 0) { u00 = 0.f; u01 = 0.f; }
        if (bh == 9) { u20 = 0.f; u21 = 0.f; }
        float g0 = P10 + u00 + u20;
        float g1v = P11 + u01 + u21;
        if (act) {
            float2 st; st.x = g0; st.y = g1v;
            *(float2*)&g1out[(size_t)bn * 10000 + (mr * 10 + wm) * 100 + bh * 10 + bw0] = st;
        }
    }
}

// Fused g2 (w2b mem-conv) + gaussian-normalize over mem + softmax + sum over
// base. One block per bn (512 x 512 thr).
__global__ __launch_bounds__(512) void k_msoft2(const float* __restrict__ g1,
                                                const float* __restrict__ w2b,
                                                float* __restrict__ attnm) {
    __shared__ float gt[10000];
    const int tid = threadIdx.x, bn = blockIdx.x;
    const float* src = g1 + (size_t)bn * 10000;
    for (int i = tid; i < 10000; i += 512) gt[i] = src[i];
    __syncthreads();
    float wb[9];
#pragma unroll
    for (int t = 0; t < 9; ++t) wb[t] = w2b[t];
    const int b = tid >> 2, q = tid & 3;
    const bool act = tid < 400;
    float ev[25];
    float se = 0.f;
    if (act) {
        float s = 0.f, ss = 0.f;
#pragma unroll
        for (int i = 0; i < 25; ++i) {
            int m = q * 25 + i, mh = m / 10, mw = m % 10;
            float v = 0.f;
#pragma unroll
            for (int dh = 0; dh < 3; ++dh) {
                int rr = mh + dh - 1;
                if ((unsigned)rr < 10u) {
#pragma unroll
                    for (int dw = 0; dw < 3; ++dw) {
                        int ww = mw + dw - 1;
                        if ((unsigned)ww < 10u)
                            v = fmaf(wb[dh * 3 + dw], gt[(rr * 10 + ww) * 100 + b], v);
                    }
                }
            }
            ev[i] = v;
            s += v; ss = fmaf(v, v, ss);
        }
        s += __shfl_xor(s, 1); s += __shfl_xor(s, 2);
        ss += __shfl_xor(ss, 1); ss += __shfl_xor(ss, 2);
        float mean = s * 0.01f;
        float var = (ss - 100.f * mean * mean) * (1.f / 99.f);
        float istd = 0.2f / sqrtf(var + 1e-5f);  // includes 1/TEMP
        float mx = -1e30f;
#pragma unroll
        for (int i = 0; i < 25; ++i) mx = fmaxf(mx, ev[i]);
        mx = fmaxf(mx, __shfl_xor(mx, 1)); mx = fmaxf(mx, __shfl_xor(mx, 2));
#pragma unroll
        for (int i = 0; i < 25; ++i) {
            float e = expf((ev[i] - mx) * istd);
            ev[i] = e; se += e;
        }
        se += __shfl_xor(se, 1); se += __shfl_xor(se, 2);
    }
    __syncthreads();   // all conv reads of gt done
    if (act) {
        float inv = 1.f / se;
#pragma unroll
        for (int i = 0; i < 25; ++i) gt[(q * 25 + i) * 100 + b] = ev[i] * inv;
    }
    __syncthreads();
    if (act) {
        int m = tid >> 2;
        float s2 = 0.f;
#pragma unroll
        for (int i = 0; i < 25; ++i) s2 += gt[m * 100 + q * 25 + i];
        s2 += __shfl_xor(s2, 1); s2 += __shfl_xor(s2, 2);
        if (q == 0) attnm[bn * 100 + m] = s2;
    }
}

// grid (64 n, 4 c-chunks), block 128.
__global__ __launch_bounds__(128) void k_attmem(const float* __restrict__ attnm,
                                                const float* __restrict__ feat_m,
                                                float* __restrict__ attm) {
    __shared__ float A[8][100];
    int n = blockIdx.x, cq = blockIdx.y, tid = threadIdx.x;
    for (int i = tid; i < 800; i += 128) {
        int b = i / 100, m = i % 100;
        A[b][m] = attnm[(b * 64 + n) * 100 + m];
    }
    __syncthreads();
    int c = cq * 128 + tid;
    const float* fp = feat_m + ((size_t)n * 512 + c) * 100;
    float acc[8] = {};
    for (int m4 = 0; m4 < 100; m4 += 4) {
        float4 v = *(const float4*)&fp[m4];
#pragma unroll
        for (int b = 0; b < 8; ++b) {
            acc[b] = fmaf(A[b][m4], v.x, acc[b]);
            acc[b] = fmaf(A[b][m4 + 1], v.y, acc[b]);
            acc[b] = fmaf(A[b][m4 + 2], v.z, acc[b]);
            acc[b] = fmaf(A[b][m4 + 3], v.w, acc[b]);
        }
    }
#pragma unroll
    for (int b = 0; b < 8; ++b)
        attm[((size_t)(b * 64 + n)) * 512 + c] = acc[b] * 0.01f;
}

// Fused enc + memory-wrap head. One block per b (8 blocks, 512 threads).
__global__ __launch_bounds__(512) void k_final(const float* __restrict__ feat_b,
                                               const float* __restrict__ attm,
                                               const float* __restrict__ w_fc,
                                               const float* __restrict__ b_fc,
                                               float* __restrict__ out) {
    __shared__ float attL[64 * 513];
    __shared__ float encL[512];
    __shared__ float mv[512];
    __shared__ float wL[64];
    __shared__ float red[512];
    __shared__ float scL[64];
    int b = blockIdx.x, tid = threadIdx.x;
    {
        const float* fp = feat_b + ((size_t)b * 512 + tid) * 100;
        float s = 0.f;
        for (int m = 0; m < 100; m += 4) {
            float4 v = *(const float4*)&fp[m];
            s += v.x + v.y + v.z + v.w;
        }
        float e = s * 0.01f;
        encL[tid] = e;
        red[tid] = e * e;
    }
    const float* ap = attm + (size_t)b * 32768;
    for (int i = tid; i < 32768; i += 512) attL[(i >> 9) * 513 + (i & 511)] = ap[i];
    __syncthreads();
    for (int o = 256; o; o >>= 1) {
        if (tid < o) red[tid] += red[tid + o];
        __syncthreads();
    }
    float escale = 1.f / fmaxf(sqrtf(red[0]), 1e-8f);
    // cosine scores: 512 threads = (n, 8 c-chunks), shuffle-combine chunks
    {
        int n = tid >> 3, o = tid & 7;
        float ss = 0.f, dp = 0.f;
#pragma unroll 4
        for (int k = 0; k < 64; ++k) {
            int c = o + 8 * ((k + n) & 63);   // rotated to spread LDS banks
            float a = attL[n * 513 + c];
            ss = fmaf(a, a, ss);
            dp = fmaf(encL[c], a, dp);
        }
        ss += __shfl_xor(ss, 1); ss += __shfl_xor(ss, 2); ss += __shfl_xor(ss, 4);
        dp += __shfl_xor(dp, 1); dp += __shfl_xor(dp, 2); dp += __shfl_xor(dp, 4);
        if (o == 0) scL[n] = dp * escale / fmaxf(sqrtf(ss), 1e-8f);
    }
    __syncthreads();
    if (tid < 64) {
        float sc = scL[tid];
        float mx = sc;
#pragma unroll
        for (int o = 32; o; o >>= 1) mx = fmaxf(mx, __shfl_xor(mx, o));
        float e = expf(sc - mx);
        float seL = e;
#pragma unroll
        for (int o = 32; o; o >>= 1) seL += __shfl_xor(seL, o);
        wL[tid] = e / seL;
    }
    __syncthreads();
    {
        int c = tid;
        float s = 0.f;
        for (int n = 0; n < 64; ++n) s = fmaf(wL[n], attL[n * 513 + c], s);
        mv[c] = s;
    }
    __syncthreads();
    for (int k = tid; k < 100; k += 512) {
        const float* wp = w_fc + (size_t)k * 1024;
        float acc = b_fc[k];
        for (int c = 0; c < 512; c += 4) {
            float4 w0 = *(const float4*)&wp[c];
            float4 w1 = *(const float4*)&wp[512 + c];
            acc = fmaf(encL[c], w0.x, acc);     acc = fmaf(encL[c + 1], w0.y, acc);
            acc = fmaf(encL[c + 2], w0.z, acc); acc = fmaf(encL[c + 3], w0.w, acc);
            acc = fmaf(mv[c], w1.x, acc);       acc = fmaf(mv[c + 1], w1.y, acc);
            acc = fmaf(mv[c + 2], w1.z, acc);   acc = fmaf(mv[c + 3], w1.w, acc);
        }
        out[b * 100 + k] = acc;
    }
}

extern "C" void kernel_launch(void* const* d_in, const int* in_sizes, int n_in,
                              void* d_out, int out_size, void* d_ws, size_t ws_size,
                              hipStream_t stream) {
    const float* feat_b = (const float*)d_in[0];
    const float* feat_m = (const float*)d_in[1];
    const float* w1x1   = (const float*)d_in[2];
    const float* gamma  = (const float*)d_in[3];
    const float* beta   = (const float*)d_in[4];
    const float* w1a    = (const float*)d_in[5];
    const float* w1b    = (const float*)d_in[6];
    const float* w2a    = (const float*)d_in[7];
    const float* w2b    = (const float*)d_in[8];
    const float* w_fc   = (const float*)d_in[9];
    const float* b_fc   = (const float*)d_in[10];

    float* ws    = (float*)d_ws;
    float* K1w   = ws;                     // 1728 (pad 1760)
    float* fbp   = ws + 1760;              // 51200
    float* fmp   = fbp + 51200;            // 409600
    float* corr  = fmp + 409600;           // 5120000
    float* g1    = corr + 5120000;         // 5120000
    float* attnm = g1 + 5120000;           // 51200
    float* attm  = attnm + 51200;          // 262144

    hipLaunchKernelGGL(k_proj2, dim3(73), dim3(512), 0, stream,
                       feat_b, feat_m, w1x1, gamma, beta, w1a, w1b, K1w, fbp, fmp);
    hipLaunchKernelGGL(k_corr, dim3(512), dim3(512), 0, stream, fbp, fmp, corr);
    hipLaunchKernelGGL(k_cca, dim3(10, 256, 2), dim3(128), 0, stream,
                       corr, K1w, w2a, g1);
    hipLaunchKernelGGL(k_msoft2, dim3(512), dim3(512), 0, stream, g1, w2b, attnm);
    hipLaunchKernelGGL(k_attmem, dim3(64, 4), dim3(128), 0, stream, attnm, feat_m, attm);
    hipLaunchKernelGGL(k_final, dim3(8), dim3(512), 0, stream,
                       feat_b, attm, w_fc, b_fc, (float*)d_out);
}

// Round 12
// 444.894 us; speedup vs baseline: 19.8955x; 19.8955x over previous
//
#include <hip/hip_runtime.h>
#include <hip/hip_bf16.h>

// ---------------------------------------------------------------------------
// CCAMemoryModel forward, f32 throughout.
//  k_proj2 : per-image tiled GEMM proj (mean-shift+BN+ReLU+L2norm);
//            block 72 composes Winograd K1w, layout [tap*64 + j*16 + c]
//            (round-8 layout; scalar-read friendly).
//  k_corr  : per (b,n) 100x100x64 GEMM -> corr[bn][m][bpos].
//  k_cca   : EXACT round-8 body (173 us known-good) with ONE delta:
//            K1w + w2a staged into LDS (scalar reads, identical indices).
//            Kills ~1300 global VMEM weight loads per mr per wave.
//  k_msoft2: fused g2 mem-conv (w2b) + gaussian-normalize + softmax over mem
//            + sum over base -> attn_memory.
//  k_attmem: att_mem[b,n,c]
//  k_final : enc + cosine weights (parallel over 512 thr) + softmax +
//            mem_vec + linear head
// ---------------------------------------------------------------------------

// Blocks 0..71: proj per image. Block 72: Winograd filter transform K1w.
__global__ __launch_bounds__(512) void k_proj2(const float* __restrict__ feat_b,
                                               const float* __restrict__ feat_m,
                                               const float* __restrict__ w1x1,
                                               const float* __restrict__ gamma,
                                               const float* __restrict__ beta,
                                               const float* __restrict__ w1a,
                                               const float* __restrict__ w1b,
                                               float* __restrict__ K1w,
                                               float* __restrict__ fbp,
                                               float* __restrict__ fmp) {
    __shared__ __align__(16) float xt[64][104];   // c-tile of x; reused as zbuf
    __shared__ __align__(16) float wt[64][68];    // c-tile of w1x1
    __shared__ float colsum[100];
    __shared__ float wsumL[64];
    __shared__ float invL[100];
    const int tid = threadIdx.x;
    const int img = blockIdx.x;
    if (img == 72) {
        // K1w[tap*64 + j*16 + c], tap = dm*3+dbh, j = Winograd coeff over dbw.
        for (int t = tid; t < 432; t += 512) {
            int tap = t >> 4, c = t & 15;
            int dm = tap / 3, dbh = tap % 3;
            float g0 = 0.f, g1 = 0.f, g2 = 0.f;
            for (int cp = 0; cp < 16; ++cp) {
                float wb = w1b[(c * 16 + cp) * 9 + dm];
                g0 = fmaf(wb, w1a[cp * 9 + dbh * 3 + 0], g0);
                g1 = fmaf(wb, w1a[cp * 9 + dbh * 3 + 1], g1);
                g2 = fmaf(wb, w1a[cp * 9 + dbh * 3 + 2], g2);
            }
            int base = tap * 64 + c;
            K1w[base]      = g0;
            K1w[base + 16] = 0.5f * (g0 + g1 + g2);
            K1w[base + 32] = 0.5f * (g0 - g1 + g2);
            K1w[base + 48] = g2;
        }
        return;
    }
    const float* x;
    float* outp;
    if (img < 8) { x = feat_b + (size_t)img * 51200; outp = fbp + (size_t)img * 6400; }
    else         { x = feat_m + (size_t)(img - 8) * 51200; outp = fmp + (size_t)(img - 8) * 6400; }

    if (tid < 100) colsum[tid] = 0.f;
    if (tid < 64) wsumL[tid] = 0.f;
    const int r = tid >> 3, q = tid & 7;   // r: out-channel, q: hw-strip
    float acc[13];
#pragma unroll
    for (int j = 0; j < 13; ++j) acc[j] = 0.f;
    __syncthreads();

    for (int ct = 0; ct < 8; ++ct) {
        for (int i = tid; i < 1600; i += 512) {
            int row = i / 25, c4 = (i % 25) * 4;
            *(float4*)&xt[row][c4] = *(const float4*)&x[(size_t)(ct * 64 + row) * 100 + c4];
        }
        for (int i = tid; i < 1024; i += 512) {
            int row = i / 16, c4 = (i % 16) * 4;
            *(float4*)&wt[row][c4] = *(const float4*)&w1x1[(size_t)row * 512 + ct * 64 + c4];
        }
        __syncthreads();
        if (tid < 100) {
            float s = 0.f;
            for (int c = 0; c < 64; ++c) s += xt[c][tid];
            colsum[tid] += s;
        }
        if (tid < 64) {
            float s = 0.f;
            for (int c = 0; c < 64; ++c) s += wt[tid][c];
            wsumL[tid] += s;
        }
        for (int c = 0; c < 64; ++c) {
            float w = wt[r][c];
#pragma unroll
            for (int j = 0; j < 13; ++j) {
                int hw = q + 8 * j;
                if (hw < 100) acc[j] = fmaf(w, xt[c][hw], acc[j]);
            }
        }
        __syncthreads();
    }
    float g = gamma[r], be = beta[r], wsr = wsumL[r];
#pragma unroll
    for (int j = 0; j < 13; ++j) {
        int hw = q + 8 * j;
        if (hw < 100) {
            float mean = colsum[hw] * (1.f / 512.f);
            xt[r][hw] = fmaxf((acc[j] - mean * wsr) * g + be, 0.f);
        }
    }
    __syncthreads();
    if (tid < 100) {
        float ss = 0.f;
        for (int rr = 0; rr < 64; ++rr) { float z = xt[rr][tid]; ss = fmaf(z, z, ss); }
        invL[tid] = 1.f / fmaxf(sqrtf(ss), 1e-8f);
    }
    __syncthreads();
    for (int i = tid; i < 6400; i += 512) {
        int rr = i / 100, hw = i % 100;
        outp[i] = xt[rr][hw] * invL[hw];
    }
}

// corr[bn][m][b] = sum_r fm[r][m]*fb[r][b]. 512 blocks.
__global__ __launch_bounds__(512) void k_corr(const float* __restrict__ fbp,
                                              const float* __restrict__ fmp,
                                              float* __restrict__ corr) {
    __shared__ __align__(16) float A[6400];
    __shared__ __align__(16) float B[6400];
    const int tid = threadIdx.x, bn = blockIdx.x;
    const float* fm = fmp + (size_t)(bn & 63) * 6400;
    const float* fb = fbp + (size_t)(bn >> 6) * 6400;
    for (int i = tid * 4; i < 6400; i += 2048) {
        *(float4*)&A[i] = *(const float4*)&fm[i];
        *(float4*)&B[i] = *(const float4*)&fb[i];
    }
    __syncthreads();
    float* dst = corr + (size_t)bn * 10000;
    for (int u = tid; u < 625; u += 512) {
        int m0 = (u / 25) * 4, b0 = (u % 25) * 4;
        float acc[4][4] = {};
        for (int r = 0; r < 64; ++r) {
            float4 av = *(const float4*)&A[r * 100 + m0];
            float4 bv = *(const float4*)&B[r * 100 + b0];
            float a[4] = {av.x, av.y, av.z, av.w};
            float bb[4] = {bv.x, bv.y, bv.z, bv.w};
#pragma unroll
            for (int i = 0; i < 4; ++i)
#pragma unroll
                for (int j = 0; j < 4; ++j) acc[i][j] = fmaf(a[i], bb[j], acc[i][j]);
        }
#pragma unroll
        for (int i = 0; i < 4; ++i)
#pragma unroll
            for (int j = 0; j < 4; ++j) dst[(m0 + i) * 100 + (b0 + j)] = acc[i][j];
    }
}

// 2 waves/block, wave = (wm, bn = 2*by+wv, half). grid (10, 256, 2), block 128.
// EXACT round-8 body; only delta: K1w/w2a staged to LDS (scalar reads,
// identical indices, short live ranges -> no spill).
__global__ __launch_bounds__(128, 4) void k_cca(const float* __restrict__ corr,
                                                const float* __restrict__ K1w,
                                                const float* __restrict__ w2a,
                                                float* __restrict__ g1out) {
    __shared__ float ringAll[2][1512];
    __shared__ float zslab[168];
    __shared__ float K1s[1728];
    __shared__ float w2s[144];
    const int tid = threadIdx.x;
    const int lane = tid & 63;
    const int wv = tid >> 6;
    const int wm = blockIdx.x;
    const int bn = blockIdx.y * 2 + wv;
    const int half = blockIdx.z;
    const int mr_lo = half * 5;
    const int Rmax = half ? 9 : 5;
    float* ring = ringAll[wv];

    for (int i = lane; i < 1512; i += 64) ring[i] = 0.f;
    for (int i = tid; i < 168; i += 128) zslab[i] = 0.f;
    for (int i = tid; i < 1728; i += 128) K1s[i] = K1w[i];
    for (int i = tid; i < 144; i += 128) w2s[i] = w2a[i];

    const int u = lane < 50 ? lane : 49;   // clamp spare lanes
    const int bh = u / 5, p = u % 5, bw0 = 2 * p;
    const bool act = lane < 50;

    const float* cbase = corr + (size_t)bn * 10000 + (wm - 1) * 100;
    const int i0 = (wm == 0) ? 100 : 0;
    const int i1 = (wm == 9) ? 200 : 300;

    auto prefetch = [&](int R) {
        const float* src = cbase + R * 1000;
        float* dslot = &ring[(R % 3) * 504];
#pragma unroll
        for (int k = 0; k < 5; ++k) {
            int i = lane + k * 64;
            if (i >= i0 && i < i1) {
                int mc = i / 100, t = i % 100;
                dslot[mc * 168 + (t / 10 + 1) * 14 + (t % 10 + 1)] = src[i];
            }
        }
    };
    __syncthreads();   // zslab/K1s/w2s staged (written by both waves)

    if (mr_lo > 0) prefetch(mr_lo - 1);
    prefetch(mr_lo);

    const int rbase = bh * 14 + bw0;
#pragma unroll
    for (int j = 0; j < 5; ++j) {
        const int mr = mr_lo + j;
        if (mr + 1 <= Rmax) prefetch(mr + 1);   // slot (mr+1)%3: row mr-2, dead

        // ---- h pass: Winograd F(2,3) over bw, 4 accumulator banks ----
        float A1[16], A2[16], A3[16], A4[16];
#pragma unroll
        for (int c = 0; c < 16; ++c) { A1[c] = 0.f; A2[c] = 0.f; A3[c] = 0.f; A4[c] = 0.f; }
        for (int dmh = 0; dmh < 3; ++dmh) {
            int mrow = mr + dmh - 1;
            if ((unsigned)mrow >= 10u) continue;
            const float* slab0 = &ring[(mrow % 3) * 504];
#pragma unroll
            for (int dmw = 0; dmw < 3; ++dmw) {
                bool mv = (unsigned)(wm + dmw - 1) < 10u;
                const float* cb = (mv ? slab0 + dmw * 168 : zslab) + rbase;
                const float* kp = K1s + (dmh * 3 + dmw) * 192;
#pragma unroll
                for (int dbh = 0; dbh < 3; ++dbh) {
                    float2 lo = *(const float2*)&cb[dbh * 14];
                    float2 hi = *(const float2*)&cb[dbh * 14 + 2];
                    float t1 = lo.x - hi.x;
                    float t2 = lo.y + hi.x;
                    float t3 = hi.x - lo.y;
                    float t4 = lo.y - hi.y;
                    const float* kq = kp + dbh * 64;
#pragma unroll
                    for (int c = 0; c < 16; ++c) {
                        A1[c] = fmaf(t1, kq[c], A1[c]);
                        A2[c] = fmaf(t2, kq[16 + c], A2[c]);
                        A3[c] = fmaf(t3, kq[32 + c], A3[c]);
                        A4[c] = fmaf(t4, kq[48 + c], A4[c]);
                    }
                }
            }
        }

        // ---- g1 base-conv via in-wave shuffles (partial row sums) ----
        float P00 = 0.f, P01 = 0.f, P10 = 0.f, P11 = 0.f, P20 = 0.f, P21 = 0.f;
#pragma unroll
        for (int c = 0; c < 16; ++c) {
            float rr0 = fmaxf(A1[c] + A2[c] + A3[c], 0.f);
            float rr1 = fmaxf(A2[c] - A3[c] - A4[c], 0.f);
            float lA = __shfl(rr1, lane - 1); lA = (p > 0) ? lA : 0.f;   // col bw0-1
            float rA = __shfl(rr0, lane + 1); rA = (p < 4) ? rA : 0.f;   // col bw0+2
            const float* wq = w2s + c * 9;
            P00 = fmaf(wq[0], lA, fmaf(wq[1], rr0, fmaf(wq[2], rr1, P00)));
            P01 = fmaf(wq[0], rr0, fmaf(wq[1], rr1, fmaf(wq[2], rA, P01)));
            P10 = fmaf(wq[3], lA, fmaf(wq[4], rr0, fmaf(wq[5], rr1, P10)));
            P11 = fmaf(wq[3], rr0, fmaf(wq[4], rr1, fmaf(wq[5], rA, P11)));
            P20 = fmaf(wq[6], lA, fmaf(wq[7], rr0, fmaf(wq[8], rr1, P20)));
            P21 = fmaf(wq[6], rr0, fmaf(wq[7], rr1, fmaf(wq[8], rA, P21)));
        }
        // out row bh takes: P0 from row bh-1 (lane-5), own P1, P2 from row bh+1.
        float u00 = __shfl(P00, lane - 5), u01 = __shfl(P01, lane - 5);
        float u20 = __shfl(P20, lane + 5), u21 = __shfl(P21, lane + 5);
        if (bh == 0) { u00 = 0.f; u01 = 0.f; }
        if (bh == 9) { u20 = 0.f; u21 = 0.f; }
        float g0 = P10 + u00 + u20;
        float g1v = P11 + u01 + u21;
        if (act) {
            float2 st; st.x = g0; st.y = g1v;
            *(float2*)&g1out[(size_t)bn * 10000 + (mr * 10 + wm) * 100 + bh * 10 + bw0] = st;
        }
    }
}

// Fused g2 (w2b mem-conv) + gaussian-normalize over mem + softmax + sum over
// base. One block per bn (512 x 512 thr).
__global__ __launch_bounds__(512) void k_msoft2(const float* __restrict__ g1,
                                                const float* __restrict__ w2b,
                                                float* __restrict__ attnm) {
    __shared__ float gt[10000];
    const int tid = threadIdx.x, bn = blockIdx.x;
    const float* src = g1 + (size_t)bn * 10000;
    for (int i = tid; i < 10000; i += 512) gt[i] = src[i];
    __syncthreads();
    float wb[9];
#pragma unroll
    for (int t = 0; t < 9; ++t) wb[t] = w2b[t];
    const int b = tid >> 2, q = tid & 3;
    const bool act = tid < 400;
    float ev[25];
    float se = 0.f;
    if (act) {
        float s = 0.f, ss = 0.f;
#pragma unroll
        for (int i = 0; i < 25; ++i) {
            int m = q * 25 + i, mh = m / 10, mw = m % 10;
            float v = 0.f;
#pragma unroll
            for (int dh = 0; dh < 3; ++dh) {
                int rr = mh + dh - 1;
                if ((unsigned)rr < 10u) {
#pragma unroll
                    for (int dw = 0; dw < 3; ++dw) {
                        int ww = mw + dw - 1;
                        if ((unsigned)ww < 10u)
                            v = fmaf(wb[dh * 3 + dw], gt[(rr * 10 + ww) * 100 + b], v);
                    }
                }
            }
            ev[i] = v;
            s += v; ss = fmaf(v, v, ss);
        }
        s += __shfl_xor(s, 1); s += __shfl_xor(s, 2);
        ss += __shfl_xor(ss, 1); ss += __shfl_xor(ss, 2);
        float mean = s * 0.01f;
        float var = (ss - 100.f * mean * mean) * (1.f / 99.f);
        float istd = 0.2f / sqrtf(var + 1e-5f);  // includes 1/TEMP
        float mx = -1e30f;
#pragma unroll
        for (int i = 0; i < 25; ++i) mx = fmaxf(mx, ev[i]);
        mx = fmaxf(mx, __shfl_xor(mx, 1)); mx = fmaxf(mx, __shfl_xor(mx, 2));
#pragma unroll
        for (int i = 0; i < 25; ++i) {
            float e = expf((ev[i] - mx) * istd);
            ev[i] = e; se += e;
        }
        se += __shfl_xor(se, 1); se += __shfl_xor(se, 2);
    }
    __syncthreads();   // all conv reads of gt done
    if (act) {
        float inv = 1.f / se;
#pragma unroll
        for (int i = 0; i < 25; ++i) gt[(q * 25 + i) * 100 + b] = ev[i] * inv;
    }
    __syncthreads();
    if (act) {
        int m = tid >> 2;
        float s2 = 0.f;
#pragma unroll
        for (int i = 0; i < 25; ++i) s2 += gt[m * 100 + q * 25 + i];
        s2 += __shfl_xor(s2, 1); s2 += __shfl_xor(s2, 2);
        if (q == 0) attnm[bn * 100 + m] = s2;
    }
}

// grid (64 n, 4 c-chunks), block 128.
__global__ __launch_bounds__(128) void k_attmem(const float* __restrict__ attnm,
                                                const float* __restrict__ feat_m,
                                                float* __restrict__ attm) {
    __shared__ float A[8][100];
    int n = blockIdx.x, cq = blockIdx.y, tid = threadIdx.x;
    for (int i = tid; i < 800; i += 128) {
        int b = i / 100, m = i % 100;
        A[b][m] = attnm[(b * 64 + n) * 100 + m];
    }
    __syncthreads();
    int c = cq * 128 + tid;
    const float* fp = feat_m + ((size_t)n * 512 + c) * 100;
    float acc[8] = {};
    for (int m4 = 0; m4 < 100; m4 += 4) {
        float4 v = *(const float4*)&fp[m4];
#pragma unroll
        for (int b = 0; b < 8; ++b) {
            acc[b] = fmaf(A[b][m4], v.x, acc[b]);
            acc[b] = fmaf(A[b][m4 + 1], v.y, acc[b]);
            acc[b] = fmaf(A[b][m4 + 2], v.z, acc[b]);
            acc[b] = fmaf(A[b][m4 + 3], v.w, acc[b]);
        }
    }
#pragma unroll
    for (int b = 0; b < 8; ++b)
        attm[((size_t)(b * 64 + n)) * 512 + c] = acc[b] * 0.01f;
}

// Fused enc + memory-wrap head. One block per b (8 blocks, 512 threads).
__global__ __launch_bounds__(512) void k_final(const float* __restrict__ feat_b,
                                               const float* __restrict__ attm,
                                               const float* __restrict__ w_fc,
                                               const float* __restrict__ b_fc,
                                               float* __restrict__ out) {
    __shared__ float attL[64 * 513];
    __shared__ float encL[512];
    __shared__ float mv[512];
    __shared__ float wL[64];
    __shared__ float red[512];
    __shared__ float scL[64];
    int b = blockIdx.x, tid = threadIdx.x;
    {
        const float* fp = feat_b + ((size_t)b * 512 + tid) * 100;
        float s = 0.f;
        for (int m = 0; m < 100; m += 4) {
            float4 v = *(const float4*)&fp[m];
            s += v.x + v.y + v.z + v.w;
        }
        float e = s * 0.01f;
        encL[tid] = e;
        red[tid] = e * e;
    }
    const float* ap = attm + (size_t)b * 32768;
    for (int i = tid; i < 32768; i += 512) attL[(i >> 9) * 513 + (i & 511)] = ap[i];
    __syncthreads();
    for (int o = 256; o; o >>= 1) {
        if (tid < o) red[tid] += red[tid + o];
        __syncthreads();
    }
    float escale = 1.f / fmaxf(sqrtf(red[0]), 1e-8f);
    // cosine scores: 512 threads = (n, 8 c-chunks), shuffle-combine chunks
    {
        int n = tid >> 3, o = tid & 7;
        float ss = 0.f, dp = 0.f;
#pragma unroll 4
        for (int k = 0; k < 64; ++k) {
            int c = o + 8 * ((k + n) & 63);   // rotated to spread LDS banks
            float a = attL[n * 513 + c];
            ss = fmaf(a, a, ss);
            dp = fmaf(encL[c], a, dp);
        }
        ss += __shfl_xor(ss, 1); ss += __shfl_xor(ss, 2); ss += __shfl_xor(ss, 4);
        dp += __shfl_xor(dp, 1); dp += __shfl_xor(dp, 2); dp += __shfl_xor(dp, 4);
        if (o == 0) scL[n] = dp * escale / fmaxf(sqrtf(ss), 1e-8f);
    }
    __syncthreads();
    if (tid < 64) {
        float sc = scL[tid];
        float mx = sc;
#pragma unroll
        for (int o = 32; o; o >>= 1) mx = fmaxf(mx, __shfl_xor(mx, o));
        float e = expf(sc - mx);
        float seL = e;
#pragma unroll
        for (int o = 32; o; o >>= 1) seL += __shfl_xor(seL, o);
        wL[tid] = e / seL;
    }
    __syncthreads();
    {
        int c = tid;
        float s = 0.f;
        for (int n = 0; n < 64; ++n) s = fmaf(wL[n], attL[n * 513 + c], s);
        mv[c] = s;
    }
    __syncthreads();
    for (int k = tid; k < 100; k += 512) {
        const float* wp = w_fc + (size_t)k * 1024;
        float acc = b_fc[k];
        for (int c = 0; c < 512; c += 4) {
            float4 w0 = *(const float4*)&wp[c];
            float4 w1 = *(const float4*)&wp[512 + c];
            acc = fmaf(encL[c], w0.x, acc);     acc = fmaf(encL[c + 1], w0.y, acc);
            acc = fmaf(encL[c + 2], w0.z, acc); acc = fmaf(encL[c + 3], w0.w, acc);
            acc = fmaf(mv[c], w1.x, acc);       acc = fmaf(mv[c + 1], w1.y, acc);
            acc = fmaf(mv[c + 2], w1.z, acc);   acc = fmaf(mv[c + 3], w1.w, acc);
        }
        out[b * 100 + k] = acc;
    }
}

extern "C" void kernel_launch(void* const* d_in, const int* in_sizes, int n_in,
                              void* d_out, int out_size, void* d_ws, size_t ws_size,
                              hipStream_t stream) {
    const float* feat_b = (const float*)d_in[0];
    const float* feat_m = (const float*)d_in[1];
    const float* w1x1   = (const float*)d_in[2];
    const float* gamma  = (const float*)d_in[3];
    const float* beta   = (const float*)d_in[4];
    const float* w1a    = (const float*)d_in[5];
    const float* w1b    = (const float*)d_in[6];
    const float* w2a    = (const float*)d_in[7];
    const float* w2b    = (const float*)d_in[8];
    const float* w_fc   = (const float*)d_in[9];
    const float* b_fc   = (const float*)d_in[10];

    float* ws    = (float*)d_ws;
    float* K1w   = ws;                     // 1728 (pad 1760)
    float* fbp   = ws + 1760;              // 51200
    float* fmp   = fbp + 51200;            // 409600
    float* corr  = fmp + 409600;           // 5120000
    float* g1    = corr + 5120000;         // 5120000
    float* attnm = g1 + 5120000;           // 51200
    float* attm  = attnm + 51200;          // 262144

    hipLaunchKernelGGL(k_proj2, dim3(73), dim3(512), 0, stream,
                       feat_b, feat_m, w1x1, gamma, beta, w1a, w1b, K1w, fbp, fmp);
    hipLaunchKernelGGL(k_corr, dim3(512), dim3(512), 0, stream, fbp, fmp, corr);
    hipLaunchKernelGGL(k_cca, dim3(10, 256, 2), dim3(128), 0, stream,
                       corr, K1w, w2a, g1);
    hipLaunchKernelGGL(k_msoft2, dim3(512), dim3(512), 0, stream, g1, w2b, attnm);
    hipLaunchKernelGGL(k_attmem, dim3(64, 4), dim3(128), 0, stream, attnm, feat_m, attm);
    hipLaunchKernelGGL(k_final, dim3(8), dim3(512), 0, stream,
                       feat_b, attm, w_fc, b_fc, (float*)d_out);
}

// Round 13
// 289.406 us; speedup vs baseline: 30.5847x; 1.5373x over previous
//
#include <hip/hip_runtime.h>
#include <hip/hip_bf16.h>

// ---------------------------------------------------------------------------
// CCAMemoryModel forward, f32 throughout.
//  k_proj2 : per-image-half tiled GEMM proj (mean-shift+BN+ReLU+L2norm);
//            grid 145: blocks 0..143 = (img, hw-half), block 144 = K1w compose.
//  k_corr  : per (b,n) 100x100x64 GEMM -> corr[bn][m][bpos].
//  k_cca   : round-8 body (173us known-good): 2 waves/block, wave =
//            (wm, bn, mr-half) strip, 3-slot ring, Winograd F(2,3) h-pass,
//            g1 via in-wave shuffles. Weights read from GLOBAL (s_load
//            scalarized — LDS staging regresses, proven r11/r12).
//            Delta vs r8: wave-uniform dmw boundary skip (exact math).
//  k_msoft2: fused g2 mem-conv + gaussian-normalize + softmax + base-sum.
//  k_attmem: att_mem[b,n,c]
//  k_final : enc + parallel cosine weights + softmax + mem_vec + head.
// ---------------------------------------------------------------------------

// Blocks 0..143: proj per (img, hw-half). Block 144: Winograd K1w.
__global__ __launch_bounds__(512) void k_proj2(const float* __restrict__ feat_b,
                                               const float* __restrict__ feat_m,
                                               const float* __restrict__ w1x1,
                                               const float* __restrict__ gamma,
                                               const float* __restrict__ beta,
                                               const float* __restrict__ w1a,
                                               const float* __restrict__ w1b,
                                               float* __restrict__ K1w,
                                               float* __restrict__ fbp,
                                               float* __restrict__ fmp) {
    __shared__ __align__(16) float xt[64][52];    // c-tile of x (one hw-half)
    __shared__ __align__(16) float wt[64][68];    // c-tile of w1x1
    __shared__ float colsum[52];
    __shared__ float wsumL[64];
    __shared__ float invL[52];
    const int tid = threadIdx.x;
    if (blockIdx.x == 144) {
        // K1w[tap*64 + j*16 + c], tap = dm*3+dbh, j = Winograd coeff over dbw.
        for (int t = tid; t < 432; t += 512) {
            int tap = t >> 4, c = t & 15;
            int dm = tap / 3, dbh = tap % 3;
            float g0 = 0.f, g1 = 0.f, g2 = 0.f;
            for (int cp = 0; cp < 16; ++cp) {
                float wb = w1b[(c * 16 + cp) * 9 + dm];
                g0 = fmaf(wb, w1a[cp * 9 + dbh * 3 + 0], g0);
                g1 = fmaf(wb, w1a[cp * 9 + dbh * 3 + 1], g1);
                g2 = fmaf(wb, w1a[cp * 9 + dbh * 3 + 2], g2);
            }
            int base = tap * 64 + c;
            K1w[base]      = g0;
            K1w[base + 16] = 0.5f * (g0 + g1 + g2);
            K1w[base + 32] = 0.5f * (g0 - g1 + g2);
            K1w[base + 48] = g2;
        }
        return;
    }
    const int img = blockIdx.x >> 1;
    const int hw0 = (blockIdx.x & 1) * 50;
    const float* x;
    float* outp;
    if (img < 8) { x = feat_b + (size_t)img * 51200; outp = fbp + (size_t)img * 6400; }
    else         { x = feat_m + (size_t)(img - 8) * 51200; outp = fmp + (size_t)(img - 8) * 6400; }

    if (tid < 50) colsum[tid] = 0.f;
    if (tid < 64) wsumL[tid] = 0.f;
    const int r = tid >> 3, q = tid & 7;   // r: out-channel, q: hw-strip
    float acc[7];
#pragma unroll
    for (int j = 0; j < 7; ++j) acc[j] = 0.f;
    __syncthreads();

    for (int ct = 0; ct < 8; ++ct) {
        for (int i = tid; i < 1600; i += 512) {   // 64 rows x 25 float2 = 50 cols
            int row = i / 25, c2 = (i % 25) * 2;
            *(float2*)&xt[row][c2] =
                *(const float2*)&x[(size_t)(ct * 64 + row) * 100 + hw0 + c2];
        }
        for (int i = tid; i < 1024; i += 512) {
            int row = i / 16, c4 = (i % 16) * 4;
            *(float4*)&wt[row][c4] = *(const float4*)&w1x1[(size_t)row * 512 + ct * 64 + c4];
        }
        __syncthreads();
        if (tid < 50) {
            float s = 0.f;
            for (int c = 0; c < 64; ++c) s += xt[c][tid];
            colsum[tid] += s;
        }
        if (tid < 64) {
            float s = 0.f;
            for (int c = 0; c < 64; ++c) s += wt[tid][c];
            wsumL[tid] += s;
        }
        for (int c = 0; c < 64; ++c) {
            float w = wt[r][c];
#pragma unroll
            for (int j = 0; j < 7; ++j) {
                int hwl = q + 8 * j;
                if (hwl < 50) acc[j] = fmaf(w, xt[c][hwl], acc[j]);
            }
        }
        __syncthreads();
    }
    float g = gamma[r], be = beta[r], wsr = wsumL[r];
#pragma unroll
    for (int j = 0; j < 7; ++j) {
        int hwl = q + 8 * j;
        if (hwl < 50) {
            float mean = colsum[hwl] * (1.f / 512.f);
            xt[r][hwl] = fmaxf((acc[j] - mean * wsr) * g + be, 0.f);
        }
    }
    __syncthreads();
    if (tid < 50) {
        float ss = 0.f;
        for (int rr = 0; rr < 64; ++rr) { float z = xt[rr][tid]; ss = fmaf(z, z, ss); }
        invL[tid] = 1.f / fmaxf(sqrtf(ss), 1e-8f);
    }
    __syncthreads();
    for (int i = tid; i < 3200; i += 512) {
        int rr = i / 50, hwl = i % 50;
        outp[rr * 100 + hw0 + hwl] = xt[rr][hwl] * invL[hwl];
    }
}

// corr[bn][m][b] = sum_r fm[r][m]*fb[r][b]. 512 blocks.
__global__ __launch_bounds__(512) void k_corr(const float* __restrict__ fbp,
                                              const float* __restrict__ fmp,
                                              float* __restrict__ corr) {
    __shared__ __align__(16) float A[6400];
    __shared__ __align__(16) float B[6400];
    const int tid = threadIdx.x, bn = blockIdx.x;
    const float* fm = fmp + (size_t)(bn & 63) * 6400;
    const float* fb = fbp + (size_t)(bn >> 6) * 6400;
    for (int i = tid * 4; i < 6400; i += 2048) {
        *(float4*)&A[i] = *(const float4*)&fm[i];
        *(float4*)&B[i] = *(const float4*)&fb[i];
    }
    __syncthreads();
    float* dst = corr + (size_t)bn * 10000;
    for (int u = tid; u < 625; u += 512) {
        int m0 = (u / 25) * 4, b0 = (u % 25) * 4;
        float acc[4][4] = {};
        for (int r = 0; r < 64; ++r) {
            float4 av = *(const float4*)&A[r * 100 + m0];
            float4 bv = *(const float4*)&B[r * 100 + b0];
            float a[4] = {av.x, av.y, av.z, av.w};
            float bb[4] = {bv.x, bv.y, bv.z, bv.w};
#pragma unroll
            for (int i = 0; i < 4; ++i)
#pragma unroll
                for (int j = 0; j < 4; ++j) acc[i][j] = fmaf(a[i], bb[j], acc[i][j]);
        }
#pragma unroll
        for (int i = 0; i < 4; ++i)
#pragma unroll
            for (int j = 0; j < 4; ++j) dst[(m0 + i) * 100 + (b0 + j)] = acc[i][j];
    }
}

// 2 waves/block, wave = (wm, bn = 2*by+wv, half). grid (10, 256, 2), block 128.
// Round-8 body; weights from global (s_load). Wave-uniform dmw boundary skip.
__global__ __launch_bounds__(128, 4) void k_cca(const float* __restrict__ corr,
                                                const float* __restrict__ K1w,
                                                const float* __restrict__ w2a,
                                                float* __restrict__ g1out) {
    __shared__ float ringAll[2][1512];
    const int tid = threadIdx.x;
    const int lane = tid & 63;
    const int wv = tid >> 6;
    const int wm = blockIdx.x;
    const int bn = blockIdx.y * 2 + wv;
    const int half = blockIdx.z;
    const int mr_lo = half * 5;
    const int Rmax = half ? 9 : 5;
    float* ring = ringAll[wv];

    for (int i = lane; i < 1512; i += 64) ring[i] = 0.f;

    const int u = lane < 50 ? lane : 49;   // clamp spare lanes
    const int bh = u / 5, p = u % 5, bw0 = 2 * p;
    const bool act = lane < 50;

    const float* cbase = corr + (size_t)bn * 10000 + (wm - 1) * 100;
    const int i0 = (wm == 0) ? 100 : 0;
    const int i1 = (wm == 9) ? 200 : 300;

    auto prefetch = [&](int R) {
        const float* src = cbase + R * 1000;
        float* dslot = &ring[(R % 3) * 504];
#pragma unroll
        for (int k = 0; k < 5; ++k) {
            int i = lane + k * 64;
            if (i >= i0 && i < i1) {
                int mc = i / 100, t = i % 100;
                dslot[mc * 168 + (t / 10 + 1) * 14 + (t % 10 + 1)] = src[i];
            }
        }
    };
    // no cross-wave shared state: no barrier needed (per-wave ring, in-order DS)

    if (mr_lo > 0) prefetch(mr_lo - 1);
    prefetch(mr_lo);

    const int rbase = bh * 14 + bw0;
#pragma unroll
    for (int j = 0; j < 5; ++j) {
        const int mr = mr_lo + j;
        if (mr + 1 <= Rmax) prefetch(mr + 1);   // slot (mr+1)%3: row mr-2, dead

        // ---- h pass: Winograd F(2,3) over bw, 4 accumulator banks ----
        float A1[16], A2[16], A3[16], A4[16];
#pragma unroll
        for (int c = 0; c < 16; ++c) { A1[c] = 0.f; A2[c] = 0.f; A3[c] = 0.f; A4[c] = 0.f; }
        for (int dmh = 0; dmh < 3; ++dmh) {
            int mrow = mr + dmh - 1;
            if ((unsigned)mrow >= 10u) continue;
            const float* slab0 = &ring[(mrow % 3) * 504];
#pragma unroll
            for (int dmw = 0; dmw < 3; ++dmw) {
                if ((unsigned)(wm + dmw - 1) >= 10u) continue;  // uniform skip (was zslab)
                const float* cb = slab0 + dmw * 168 + rbase;
                const float* kp = K1w + (dmh * 3 + dmw) * 192;
#pragma unroll
                for (int dbh = 0; dbh < 3; ++dbh) {
                    float2 lo = *(const float2*)&cb[dbh * 14];
                    float2 hi = *(const float2*)&cb[dbh * 14 + 2];
                    float t1 = lo.x - hi.x;
                    float t2 = lo.y + hi.x;
                    float t3 = hi.x - lo.y;
                    float t4 = lo.y - hi.y;
                    const float* kq = kp + dbh * 64;
#pragma unroll
                    for (int c = 0; c < 16; ++c) {
                        A1[c] = fmaf(t1, kq[c], A1[c]);
                        A2[c] = fmaf(t2, kq[16 + c], A2[c]);
                        A3[c] = fmaf(t3, kq[32 + c], A3[c]);
                        A4[c] = fmaf(t4, kq[48 + c], A4[c]);
                    }
                }
            }
        }

        // ---- g1 base-conv via in-wave shuffles (partial row sums) ----
        float P00 = 0.f, P01 = 0.f, P10 = 0.f, P11 = 0.f, P20 = 0.f, P21 = 0.f;
#pragma unroll
        for (int c = 0; c < 16; ++c) {
            float rr0 = fmaxf(A1[c] + A2[c] + A3[c], 0.f);
            float rr1 = fmaxf(A2[c] - A3[c] - A4[c], 0.f);
            float lA = __shfl(rr1, lane - 1); lA = (p > 0) ? lA : 0.f;   // col bw0-1
            float rA = __shfl(rr0, lane + 1); rA = (p < 4) ? rA : 0.f;   // col bw0+2
            const float* wq = w2a + c * 9;
            P00 = fmaf(wq[0], lA, fmaf(wq[1], rr0, fmaf(wq[2], rr1, P00)));
            P01 = fmaf(wq[0], rr0, fmaf(wq[1], rr1, fmaf(wq[2], rA, P01)));
            P10 = fmaf(wq[3], lA, fmaf(wq[4], rr0, fmaf(wq[5], rr1, P10)));
            P11 = fmaf(wq[3], rr0, fmaf(wq[4], rr1, fmaf(wq[5], rA, P11)));
            P20 = fmaf(wq[6], lA, fmaf(wq[7], rr0, fmaf(wq[8], rr1, P20)));
            P21 = fmaf(wq[6], rr0, fmaf(wq[7], rr1, fmaf(wq[8], rA, P21)));
        }
        // out row bh takes: P0 from row bh-1 (lane-5), own P1, P2 from row bh+1.
        float u00 = __shfl(P00, lane - 5), u01 = __shfl(P01, lane - 5);
        float u20 = __shfl(P20, lane + 5), u21 = __shfl(P21, lane + 5);
        if (bh == 0) { u00 = 0.f; u01 = 0.f; }
        if (bh == 9) { u20 = 0.f; u21 = 0.f; }
        float g0 = P10 + u00 + u20;
        float g1v = P11 + u01 + u21;
        if (act) {
            float2 st; st.x = g0; st.y = g1v;
            *(float2*)&g1out[(size_t)bn * 10000 + (mr * 10 + wm) * 100 + bh * 10 + bw0] = st;
        }
    }
}

// Fused g2 (w2b mem-conv) + gaussian-normalize over mem + softmax + sum over
// base. One block per bn (512 x 512 thr).
__global__ __launch_bounds__(512) void k_msoft2(const float* __restrict__ g1,
                                                const float* __restrict__ w2b,
                                                float* __restrict__ attnm) {
    __shared__ float gt[10000];
    const int tid = threadIdx.x, bn = blockIdx.x;
    const float* src = g1 + (size_t)bn * 10000;
    for (int i = tid; i < 10000; i += 512) gt[i] = src[i];
    __syncthreads();
    float wb[9];
#pragma unroll
    for (int t = 0; t < 9; ++t) wb[t] = w2b[t];
    const int b = tid >> 2, q = tid & 3;
    const bool act = tid < 400;
    float ev[25];
    float se = 0.f;
    if (act) {
        float s = 0.f, ss = 0.f;
#pragma unroll
        for (int i = 0; i < 25; ++i) {
            int m = q * 25 + i, mh = m / 10, mw = m % 10;
            float v = 0.f;
#pragma unroll
            for (int dh = 0; dh < 3; ++dh) {
                int rr = mh + dh - 1;
                if ((unsigned)rr < 10u) {
#pragma unroll
                    for (int dw = 0; dw < 3; ++dw) {
                        int ww = mw + dw - 1;
                        if ((unsigned)ww < 10u)
                            v = fmaf(wb[dh * 3 + dw], gt[(rr * 10 + ww) * 100 + b], v);
                    }
                }
            }
            ev[i] = v;
            s += v; ss = fmaf(v, v, ss);
        }
        s += __shfl_xor(s, 1); s += __shfl_xor(s, 2);
        ss += __shfl_xor(ss, 1); ss += __shfl_xor(ss, 2);
        float mean = s * 0.01f;
        float var = (ss - 100.f * mean * mean) * (1.f / 99.f);
        float istd = 0.2f / sqrtf(var + 1e-5f);  // includes 1/TEMP
        float mx = -1e30f;
#pragma unroll
        for (int i = 0; i < 25; ++i) mx = fmaxf(mx, ev[i]);
        mx = fmaxf(mx, __shfl_xor(mx, 1)); mx = fmaxf(mx, __shfl_xor(mx, 2));
#pragma unroll
        for (int i = 0; i < 25; ++i) {
            float e = expf((ev[i] - mx) * istd);
            ev[i] = e; se += e;
        }
        se += __shfl_xor(se, 1); se += __shfl_xor(se, 2);
    }
    __syncthreads();   // all conv reads of gt done
    if (act) {
        float inv = 1.f / se;
#pragma unroll
        for (int i = 0; i < 25; ++i) gt[(q * 25 + i) * 100 + b] = ev[i] * inv;
    }
    __syncthreads();
    if (act) {
        int m = tid >> 2;
        float s2 = 0.f;
#pragma unroll
        for (int i = 0; i < 25; ++i) s2 += gt[m * 100 + q * 25 + i];
        s2 += __shfl_xor(s2, 1); s2 += __shfl_xor(s2, 2);
        if (q == 0) attnm[bn * 100 + m] = s2;
    }
}

// grid (64 n, 4 c-chunks), block 128.
__global__ __launch_bounds__(128) void k_attmem(const float* __restrict__ attnm,
                                                const float* __restrict__ feat_m,
                                                float* __restrict__ attm) {
    __shared__ float A[8][100];
    int n = blockIdx.x, cq = blockIdx.y, tid = threadIdx.x;
    for (int i = tid; i < 800; i += 128) {
        int b = i / 100, m = i % 100;
        A[b][m] = attnm[(b * 64 + n) * 100 + m];
    }
    __syncthreads();
    int c = cq * 128 + tid;
    const float* fp = feat_m + ((size_t)n * 512 + c) * 100;
    float acc[8] = {};
    for (int m4 = 0; m4 < 100; m4 += 4) {
        float4 v = *(const float4*)&fp[m4];
#pragma unroll
        for (int b = 0; b < 8; ++b) {
            acc[b] = fmaf(A[b][m4], v.x, acc[b]);
            acc[b] = fmaf(A[b][m4 + 1], v.y, acc[b]);
            acc[b] = fmaf(A[b][m4 + 2], v.z, acc[b]);
            acc[b] = fmaf(A[b][m4 + 3], v.w, acc[b]);
        }
    }
#pragma unroll
    for (int b = 0; b < 8; ++b)
        attm[((size_t)(b * 64 + n)) * 512 + c] = acc[b] * 0.01f;
}

// Fused enc + memory-wrap head. One block per b (8 blocks, 512 threads).
__global__ __launch_bounds__(512) void k_final(const float* __restrict__ feat_b,
                                               const float* __restrict__ attm,
                                               const float* __restrict__ w_fc,
                                               const float* __restrict__ b_fc,
                                               float* __restrict__ out) {
    __shared__ float attL[64 * 513];
    __shared__ float encL[512];
    __shared__ float mv[512];
    __shared__ float wL[64];
    __shared__ float red[512];
    __shared__ float scL[64];
    int b = blockIdx.x, tid = threadIdx.x;
    {
        const float* fp = feat_b + ((size_t)b * 512 + tid) * 100;
        float s = 0.f;
        for (int m = 0; m < 100; m += 4) {
            float4 v = *(const float4*)&fp[m];
            s += v.x + v.y + v.z + v.w;
        }
        float e = s * 0.01f;
        encL[tid] = e;
        red[tid] = e * e;
    }
    const float* ap = attm + (size_t)b * 32768;
    for (int i = tid; i < 32768; i += 512) attL[(i >> 9) * 513 + (i & 511)] = ap[i];
    __syncthreads();
    for (int o = 256; o; o >>= 1) {
        if (tid < o) red[tid] += red[tid + o];
        __syncthreads();
    }
    float escale = 1.f / fmaxf(sqrtf(red[0]), 1e-8f);
    // cosine scores: 512 threads = (n, 8 c-chunks), shuffle-combine chunks
    {
        int n = tid >> 3, o = tid & 7;
        float ss = 0.f, dp = 0.f;
#pragma unroll 4
        for (int k = 0; k < 64; ++k) {
            int c = o + 8 * ((k + n) & 63);   // rotated to spread LDS banks
            float a = attL[n * 513 + c];
            ss = fmaf(a, a, ss);
            dp = fmaf(encL[c], a, dp);
        }
        ss += __shfl_xor(ss, 1); ss += __shfl_xor(ss, 2); ss += __shfl_xor(ss, 4);
        dp += __shfl_xor(dp, 1); dp += __shfl_xor(dp, 2); dp += __shfl_xor(dp, 4);
        if (o == 0) scL[n] = dp * escale / fmaxf(sqrtf(ss), 1e-8f);
    }
    __syncthreads();
    if (tid < 64) {
        float sc = scL[tid];
        float mx = sc;
#pragma unroll
        for (int o = 32; o; o >>= 1) mx = fmaxf(mx, __shfl_xor(mx, o));
        float e = expf(sc - mx);
        float seL = e;
#pragma unroll
        for (int o = 32; o; o >>= 1) seL += __shfl_xor(seL, o);
        wL[tid] = e / seL;
    }
    __syncthreads();
    {
        int c = tid;
        float s = 0.f;
        for (int n = 0; n < 64; ++n) s = fmaf(wL[n], attL[n * 513 + c], s);
        mv[c] = s;
    }
    __syncthreads();
    for (int k = tid; k < 100; k += 512) {
        const float* wp = w_fc + (size_t)k * 1024;
        float acc = b_fc[k];
        for (int c = 0; c < 512; c += 4) {
            float4 w0 = *(const float4*)&wp[c];
            float4 w1 = *(const float4*)&wp[512 + c];
            acc = fmaf(encL[c], w0.x, acc);     acc = fmaf(encL[c + 1], w0.y, acc);
            acc = fmaf(encL[c + 2], w0.z, acc); acc = fmaf(encL[c + 3], w0.w, acc);
            acc = fmaf(mv[c], w1.x, acc);       acc = fmaf(mv[c + 1], w1.y, acc);
            acc = fmaf(mv[c + 2], w1.z, acc);   acc = fmaf(mv[c + 3], w1.w, acc);
        }
        out[b * 100 + k] = acc;
    }
}

extern "C" void kernel_launch(void* const* d_in, const int* in_sizes, int n_in,
                              void* d_out, int out_size, void* d_ws, size_t ws_size,
                              hipStream_t stream) {
    const float* feat_b = (const float*)d_in[0];
    const float* feat_m = (const float*)d_in[1];
    const float* w1x1   = (const float*)d_in[2];
    const float* gamma  = (const float*)d_in[3];
    const float* beta   = (const float*)d_in[4];
    const float* w1a    = (const float*)d_in[5];
    const float* w1b    = (const float*)d_in[6];
    const float* w2a    = (const float*)d_in[7];
    const float* w2b    = (const float*)d_in[8];
    const float* w_fc   = (const float*)d_in[9];
    const float* b_fc   = (const float*)d_in[10];

    float* ws    = (float*)d_ws;
    float* K1w   = ws;                     // 1728 (pad 1760)
    float* fbp   = ws + 1760;              // 51200
    float* fmp   = fbp + 51200;            // 409600
    float* corr  = fmp + 409600;           // 5120000
    float* g1    = corr + 5120000;         // 5120000
    float* attnm = g1 + 5120000;           // 51200
    float* attm  = attnm + 51200;          // 262144

    hipLaunchKernelGGL(k_proj2, dim3(145), dim3(512), 0, stream,
                       feat_b, feat_m, w1x1, gamma, beta, w1a, w1b, K1w, fbp, fmp);
    hipLaunchKernelGGL(k_corr, dim3(512), dim3(512), 0, stream, fbp, fmp, corr);
    hipLaunchKernelGGL(k_cca, dim3(10, 256, 2), dim3(128), 0, stream,
                       corr, K1w, w2a, g1);
    hipLaunchKernelGGL(k_msoft2, dim3(512), dim3(512), 0, stream, g1, w2b, attnm);
    hipLaunchKernelGGL(k_attmem, dim3(64, 4), dim3(128), 0, stream, attnm, feat_m, attm);
    hipLaunchKernelGGL(k_final, dim3(8), dim3(512), 0, stream,
                       feat_b, attm, w_fc, b_fc, (float*)d_out);
}

// Round 14
// 283.589 us; speedup vs baseline: 31.2121x; 1.0205x over previous
//
#include <hip/hip_runtime.h>
#include <hip/hip_bf16.h>

// ---------------------------------------------------------------------------
// CCAMemoryModel forward, f32 throughout.
//  k_proj2 : per-image-half tiled GEMM proj; block 144 composes Winograd K1w.
//  k_corr  : per (b,n) 100x100x64 GEMM -> corr[bn][m][bpos].
//  k_cca   : 2 waves/block, wave = (wm, bn, mr-half) strip, 3-slot ring,
//            Winograd F(2,3) h-pass, g1 base-conv with cross-term-sum trick
//            (own-sums U/V + exported X0/X2, 10 shuffles/mr vs 36).
//            Weights from global (s_load scalarized; LDS staging proven bad).
//  k_msoft2: fused g2 mem-conv + gaussian-normalize + softmax + base-sum,
//            TRANSPOSED [b][m] staging (stride 101) for conflict-free conv.
//  k_attmem: att_mem[b,n,c]
//  k_final : enc + parallel cosine weights + softmax + mem_vec + head.
// ---------------------------------------------------------------------------

// Blocks 0..143: proj per (img, hw-half). Block 144: Winograd K1w.
__global__ __launch_bounds__(512) void k_proj2(const float* __restrict__ feat_b,
                                               const float* __restrict__ feat_m,
                                               const float* __restrict__ w1x1,
                                               const float* __restrict__ gamma,
                                               const float* __restrict__ beta,
                                               const float* __restrict__ w1a,
                                               const float* __restrict__ w1b,
                                               float* __restrict__ K1w,
                                               float* __restrict__ fbp,
                                               float* __restrict__ fmp) {
    __shared__ __align__(16) float xt[64][52];
    __shared__ __align__(16) float wt[64][68];
    __shared__ float colsum[52];
    __shared__ float wsumL[64];
    __shared__ float invL[52];
    const int tid = threadIdx.x;
    if (blockIdx.x == 144) {
        for (int t = tid; t < 432; t += 512) {
            int tap = t >> 4, c = t & 15;
            int dm = tap / 3, dbh = tap % 3;
            float g0 = 0.f, g1 = 0.f, g2 = 0.f;
            for (int cp = 0; cp < 16; ++cp) {
                float wb = w1b[(c * 16 + cp) * 9 + dm];
                g0 = fmaf(wb, w1a[cp * 9 + dbh * 3 + 0], g0);
                g1 = fmaf(wb, w1a[cp * 9 + dbh * 3 + 1], g1);
                g2 = fmaf(wb, w1a[cp * 9 + dbh * 3 + 2], g2);
            }
            int base = tap * 64 + c;
            K1w[base]      = g0;
            K1w[base + 16] = 0.5f * (g0 + g1 + g2);
            K1w[base + 32] = 0.5f * (g0 - g1 + g2);
            K1w[base + 48] = g2;
        }
        return;
    }
    const int img = blockIdx.x >> 1;
    const int hw0 = (blockIdx.x & 1) * 50;
    const float* x;
    float* outp;
    if (img < 8) { x = feat_b + (size_t)img * 51200; outp = fbp + (size_t)img * 6400; }
    else         { x = feat_m + (size_t)(img - 8) * 51200; outp = fmp + (size_t)(img - 8) * 6400; }

    if (tid < 50) colsum[tid] = 0.f;
    if (tid < 64) wsumL[tid] = 0.f;
    const int r = tid >> 3, q = tid & 7;
    float acc[7];
#pragma unroll
    for (int j = 0; j < 7; ++j) acc[j] = 0.f;
    __syncthreads();

    for (int ct = 0; ct < 8; ++ct) {
        for (int i = tid; i < 1600; i += 512) {
            int row = i / 25, c2 = (i % 25) * 2;
            *(float2*)&xt[row][c2] =
                *(const float2*)&x[(size_t)(ct * 64 + row) * 100 + hw0 + c2];
        }
        for (int i = tid; i < 1024; i += 512) {
            int row = i / 16, c4 = (i % 16) * 4;
            *(float4*)&wt[row][c4] = *(const float4*)&w1x1[(size_t)row * 512 + ct * 64 + c4];
        }
        __syncthreads();
        if (tid < 50) {
            float s = 0.f;
            for (int c = 0; c < 64; ++c) s += xt[c][tid];
            colsum[tid] += s;
        }
        if (tid < 64) {
            float s = 0.f;
            for (int c = 0; c < 64; ++c) s += wt[tid][c];
            wsumL[tid] += s;
        }
        for (int c = 0; c < 64; ++c) {
            float w = wt[r][c];
#pragma unroll
            for (int j = 0; j < 7; ++j) {
                int hwl = q + 8 * j;
                if (hwl < 50) acc[j] = fmaf(w, xt[c][hwl], acc[j]);
            }
        }
        __syncthreads();
    }
    float g = gamma[r], be = beta[r], wsr = wsumL[r];
#pragma unroll
    for (int j = 0; j < 7; ++j) {
        int hwl = q + 8 * j;
        if (hwl < 50) {
            float mean = colsum[hwl] * (1.f / 512.f);
            xt[r][hwl] = fmaxf((acc[j] - mean * wsr) * g + be, 0.f);
        }
    }
    __syncthreads();
    if (tid < 50) {
        float ss = 0.f;
        for (int rr = 0; rr < 64; ++rr) { float z = xt[rr][tid]; ss = fmaf(z, z, ss); }
        invL[tid] = 1.f / fmaxf(sqrtf(ss), 1e-8f);
    }
    __syncthreads();
    for (int i = tid; i < 3200; i += 512) {
        int rr = i / 50, hwl = i % 50;
        outp[rr * 100 + hw0 + hwl] = xt[rr][hwl] * invL[hwl];
    }
}

// corr[bn][m][b] = sum_r fm[r][m]*fb[r][b]. 512 blocks.
__global__ __launch_bounds__(512) void k_corr(const float* __restrict__ fbp,
                                              const float* __restrict__ fmp,
                                              float* __restrict__ corr) {
    __shared__ __align__(16) float A[6400];
    __shared__ __align__(16) float B[6400];
    const int tid = threadIdx.x, bn = blockIdx.x;
    const float* fm = fmp + (size_t)(bn & 63) * 6400;
    const float* fb = fbp + (size_t)(bn >> 6) * 6400;
    for (int i = tid * 4; i < 6400; i += 2048) {
        *(float4*)&A[i] = *(const float4*)&fm[i];
        *(float4*)&B[i] = *(const float4*)&fb[i];
    }
    __syncthreads();
    float* dst = corr + (size_t)bn * 10000;
    for (int u = tid; u < 625; u += 512) {
        int m0 = (u / 25) * 4, b0 = (u % 25) * 4;
        float acc[4][4] = {};
        for (int r = 0; r < 64; ++r) {
            float4 av = *(const float4*)&A[r * 100 + m0];
            float4 bv = *(const float4*)&B[r * 100 + b0];
            float a[4] = {av.x, av.y, av.z, av.w};
            float bb[4] = {bv.x, bv.y, bv.z, bv.w};
#pragma unroll
            for (int i = 0; i < 4; ++i)
#pragma unroll
                for (int j = 0; j < 4; ++j) acc[i][j] = fmaf(a[i], bb[j], acc[i][j]);
        }
#pragma unroll
        for (int i = 0; i < 4; ++i)
#pragma unroll
            for (int j = 0; j < 4; ++j) dst[(m0 + i) * 100 + (b0 + j)] = acc[i][j];
    }
}

// 2 waves/block, wave = (wm, bn = 2*by+wv, half). grid (10, 256, 2), block 128.
__global__ __launch_bounds__(128, 4) void k_cca(const float* __restrict__ corr,
                                                const float* __restrict__ K1w,
                                                const float* __restrict__ w2a,
                                                float* __restrict__ g1out) {
    __shared__ float ringAll[2][1512];
    const int tid = threadIdx.x;
    const int lane = tid & 63;
    const int wv = tid >> 6;
    const int wm = blockIdx.x;
    const int bn = blockIdx.y * 2 + wv;
    const int half = blockIdx.z;
    const int mr_lo = half * 5;
    const int Rmax = half ? 9 : 5;
    float* ring = ringAll[wv];

    for (int i = lane; i < 1512; i += 64) ring[i] = 0.f;

    const int u = lane < 50 ? lane : 49;
    const int bh = u / 5, p = u % 5, bw0 = 2 * p;
    const bool act = lane < 50;

    const float* cbase = corr + (size_t)bn * 10000 + (wm - 1) * 100;
    const int i0 = (wm == 0) ? 100 : 0;
    const int i1 = (wm == 9) ? 200 : 300;

    auto prefetch = [&](int R) {
        const float* src = cbase + R * 1000;
        float* dslot = &ring[(R % 3) * 504];
#pragma unroll
        for (int k = 0; k < 5; ++k) {
            int i = lane + k * 64;
            if (i >= i0 && i < i1) {
                int mc = i / 100, t = i % 100;
                dslot[mc * 168 + (t / 10 + 1) * 14 + (t % 10 + 1)] = src[i];
            }
        }
    };

    if (mr_lo > 0) prefetch(mr_lo - 1);
    prefetch(mr_lo);

    const int rbase = bh * 14 + bw0;
#pragma unroll
    for (int j = 0; j < 5; ++j) {
        const int mr = mr_lo + j;
        if (mr + 1 <= Rmax) prefetch(mr + 1);

        // ---- h pass: Winograd F(2,3) over bw, 4 accumulator banks ----
        float A1[16], A2[16], A3[16], A4[16];
#pragma unroll
        for (int c = 0; c < 16; ++c) { A1[c] = 0.f; A2[c] = 0.f; A3[c] = 0.f; A4[c] = 0.f; }
        for (int dmh = 0; dmh < 3; ++dmh) {
            int mrow = mr + dmh - 1;
            if ((unsigned)mrow >= 10u) continue;
            const float* slab0 = &ring[(mrow % 3) * 504];
#pragma unroll
            for (int dmw = 0; dmw < 3; ++dmw) {
                if ((unsigned)(wm + dmw - 1) >= 10u) continue;  // uniform skip
                const float* cb = slab0 + dmw * 168 + rbase;
                const float* kp = K1w + (dmh * 3 + dmw) * 192;
#pragma unroll
                for (int dbh = 0; dbh < 3; ++dbh) {
                    float2 lo = *(const float2*)&cb[dbh * 14];
                    float2 hi = *(const float2*)&cb[dbh * 14 + 2];
                    float t1 = lo.x - hi.x;
                    float t2 = lo.y + hi.x;
                    float t3 = hi.x - lo.y;
                    float t4 = lo.y - hi.y;
                    const float* kq = kp + dbh * 64;
#pragma unroll
                    for (int c = 0; c < 16; ++c) {
                        A1[c] = fmaf(t1, kq[c], A1[c]);
                        A2[c] = fmaf(t2, kq[16 + c], A2[c]);
                        A3[c] = fmaf(t3, kq[32 + c], A3[c]);
                        A4[c] = fmaf(t4, kq[48 + c], A4[c]);
                    }
                }
            }
        }

        // ---- g1 base-conv: own-sums + cross-term export (exact reorder) ----
        // Per row-tap t: P_t(col0) = U[t] + left.X0[t]; P_t(col1) = V[t] + right.X2[t]
        // where X0 = sum_c w[3t]*r1, X2 = sum_c w[3t+2]*r0.
        float U0 = 0.f, V0 = 0.f, X00 = 0.f, X20 = 0.f;
        float U1 = 0.f, V1 = 0.f, X01 = 0.f, X21 = 0.f;
        float U2 = 0.f, V2 = 0.f, X02 = 0.f, X22 = 0.f;
#pragma unroll
        for (int c = 0; c < 16; ++c) {
            float rr0 = fmaxf(A1[c] + A2[c] + A3[c], 0.f);
            float rr1 = fmaxf(A2[c] - A3[c] - A4[c], 0.f);
            const float* wq = w2a + c * 9;
            float w0 = wq[0], w1 = wq[1], w2 = wq[2];
            U0 = fmaf(w1, rr0, fmaf(w2, rr1, U0));
            V0 = fmaf(w0, rr0, fmaf(w1, rr1, V0));
            X00 = fmaf(w0, rr1, X00);
            X20 = fmaf(w2, rr0, X20);
            float w3 = wq[3], w4 = wq[4], w5 = wq[5];
            U1 = fmaf(w4, rr0, fmaf(w5, rr1, U1));
            V1 = fmaf(w3, rr0, fmaf(w4, rr1, V1));
            X01 = fmaf(w3, rr1, X01);
            X21 = fmaf(w5, rr0, X21);
            float w6 = wq[6], w7 = wq[7], w8 = wq[8];
            U2 = fmaf(w7, rr0, fmaf(w8, rr1, U2));
            V2 = fmaf(w6, rr0, fmaf(w7, rr1, V2));
            X02 = fmaf(w6, rr1, X02);
            X22 = fmaf(w8, rr0, X22);
        }
        float l0 = __shfl(X00, lane - 1), l1 = __shfl(X01, lane - 1), l2 = __shfl(X02, lane - 1);
        float r0s = __shfl(X20, lane + 1), r1s = __shfl(X21, lane + 1), r2s = __shfl(X22, lane + 1);
        bool pl = (p > 0), pr = (p < 4);
        float P00 = U0 + (pl ? l0 : 0.f), P01 = V0 + (pr ? r0s : 0.f);
        float P10 = U1 + (pl ? l1 : 0.f), P11 = V1 + (pr ? r1s : 0.f);
        float P20 = U2 + (pl ? l2 : 0.f), P21 = V2 + (pr ? r2s : 0.f);
        // out row bh takes: P0 from row bh-1 (lane-5), own P1, P2 from row bh+1.
        float u00 = __shfl(P00, lane - 5), u01 = __shfl(P01, lane - 5);
        float u20 = __shfl(P20, lane + 5), u21 = __shfl(P21, lane + 5);
        if (bh == 0) { u00 = 0.f; u01 = 0.f; }
        if (bh == 9) { u20 = 0.f; u21 = 0.f; }
        float g0 = P10 + u00 + u20;
        float g1v = P11 + u01 + u21;
        if (act) {
            float2 st; st.x = g0; st.y = g1v;
            *(float2*)&g1out[(size_t)bn * 10000 + (mr * 10 + wm) * 100 + bh * 10 + bw0] = st;
        }
    }
}

// Fused g2 (w2b mem-conv) + gaussian-normalize over mem + softmax + sum over
// base. One block per bn; TRANSPOSED staging gt[b][m] stride 101.
__global__ __launch_bounds__(512) void k_msoft2(const float* __restrict__ g1,
                                                const float* __restrict__ w2b,
                                                float* __restrict__ attnm) {
    __shared__ float gt[100 * 101];
    const int tid = threadIdx.x, bn = blockIdx.x;
    const float* src = g1 + (size_t)bn * 10000;
    for (int i = tid; i < 10000; i += 512) {
        int m = i / 100, b = i % 100;
        gt[b * 101 + m] = src[i];
    }
    __syncthreads();
    float wb[9];
#pragma unroll
    for (int t = 0; t < 9; ++t) wb[t] = w2b[t];
    const int b = tid >> 2, q = tid & 3;
    const bool act = tid < 400;
    const float* gb = &gt[b * 101];
    float ev[25];
    float se = 0.f;
    if (act) {
        float s = 0.f, ss = 0.f;
#pragma unroll
        for (int i = 0; i < 25; ++i) {
            int m = q * 25 + i, mh = m / 10, mw = m % 10;
            float v = 0.f;
#pragma unroll
            for (int dh = 0; dh < 3; ++dh) {
                int rr = mh + dh - 1;
                if ((unsigned)rr < 10u) {
#pragma unroll
                    for (int dw = 0; dw < 3; ++dw) {
                        int ww = mw + dw - 1;
                        if ((unsigned)ww < 10u)
                            v = fmaf(wb[dh * 3 + dw], gb[rr * 10 + ww], v);
                    }
                }
            }
            ev[i] = v;
            s += v; ss = fmaf(v, v, ss);
        }
        s += __shfl_xor(s, 1); s += __shfl_xor(s, 2);
        ss += __shfl_xor(ss, 1); ss += __shfl_xor(ss, 2);
        float mean = s * 0.01f;
        float var = (ss - 100.f * mean * mean) * (1.f / 99.f);
        float istd = 0.2f / sqrtf(var + 1e-5f);  // includes 1/TEMP
        float mx = -1e30f;
#pragma unroll
        for (int i = 0; i < 25; ++i) mx = fmaxf(mx, ev[i]);
        mx = fmaxf(mx, __shfl_xor(mx, 1)); mx = fmaxf(mx, __shfl_xor(mx, 2));
#pragma unroll
        for (int i = 0; i < 25; ++i) {
            float e = expf((ev[i] - mx) * istd);
            ev[i] = e; se += e;
        }
        se += __shfl_xor(se, 1); se += __shfl_xor(se, 2);
    }
    __syncthreads();   // all conv reads of gt done
    if (act) {
        float inv = 1.f / se;
        float* gw = &gt[b * 101 + q * 25];
#pragma unroll
        for (int i = 0; i < 25; ++i) gw[i] = ev[i] * inv;
    }
    __syncthreads();
    if (act) {
        int m = tid >> 2;   // output m; sum over b = q*25..q*25+24
        float s2 = 0.f;
#pragma unroll
        for (int i = 0; i < 25; ++i) s2 += gt[(q * 25 + i) * 101 + m];
        s2 += __shfl_xor(s2, 1); s2 += __shfl_xor(s2, 2);
        if (q == 0) attnm[bn * 100 + m] = s2;
    }
}

// grid (64 n, 4 c-chunks), block 128.
__global__ __launch_bounds__(128) void k_attmem(const float* __restrict__ attnm,
                                                const float* __restrict__ feat_m,
                                                float* __restrict__ attm) {
    __shared__ float A[8][100];
    int n = blockIdx.x, cq = blockIdx.y, tid = threadIdx.x;
    for (int i = tid; i < 800; i += 128) {
        int b = i / 100, m = i % 100;
        A[b][m] = attnm[(b * 64 + n) * 100 + m];
    }
    __syncthreads();
    int c = cq * 128 + tid;
    const float* fp = feat_m + ((size_t)n * 512 + c) * 100;
    float acc[8] = {};
    for (int m4 = 0; m4 < 100; m4 += 4) {
        float4 v = *(const float4*)&fp[m4];
#pragma unroll
        for (int b = 0; b < 8; ++b) {
            acc[b] = fmaf(A[b][m4], v.x, acc[b]);
            acc[b] = fmaf(A[b][m4 + 1], v.y, acc[b]);
            acc[b] = fmaf(A[b][m4 + 2], v.z, acc[b]);
            acc[b] = fmaf(A[b][m4 + 3], v.w, acc[b]);
        }
    }
#pragma unroll
    for (int b = 0; b < 8; ++b)
        attm[((size_t)(b * 64 + n)) * 512 + c] = acc[b] * 0.01f;
}

// Fused enc + memory-wrap head. One block per b (8 blocks, 512 threads).
__global__ __launch_bounds__(512) void k_final(const float* __restrict__ feat_b,
                                               const float* __restrict__ attm,
                                               const float* __restrict__ w_fc,
                                               const float* __restrict__ b_fc,
                                               float* __restrict__ out) {
    __shared__ float attL[64 * 513];
    __shared__ float encL[512];
    __shared__ float mv[512];
    __shared__ float wL[64];
    __shared__ float red[512];
    __shared__ float scL[64];
    int b = blockIdx.x, tid = threadIdx.x;
    {
        const float* fp = feat_b + ((size_t)b * 512 + tid) * 100;
        float s = 0.f;
        for (int m = 0; m < 100; m += 4) {
            float4 v = *(const float4*)&fp[m];
            s += v.x + v.y + v.z + v.w;
        }
        float e = s * 0.01f;
        encL[tid] = e;
        red[tid] = e * e;
    }
    const float* ap = attm + (size_t)b * 32768;
    for (int i = tid; i < 32768; i += 512) attL[(i >> 9) * 513 + (i & 511)] = ap[i];
    __syncthreads();
    for (int o = 256; o; o >>= 1) {
        if (tid < o) red[tid] += red[tid + o];
        __syncthreads();
    }
    float escale = 1.f / fmaxf(sqrtf(red[0]), 1e-8f);
    {
        int n = tid >> 3, o = tid & 7;
        float ss = 0.f, dp = 0.f;
#pragma unroll 4
        for (int k = 0; k < 64; ++k) {
            int c = o + 8 * ((k + n) & 63);
            float a = attL[n * 513 + c];
            ss = fmaf(a, a, ss);
            dp = fmaf(encL[c], a, dp);
        }
        ss += __shfl_xor(ss, 1); ss += __shfl_xor(ss, 2); ss += __shfl_xor(ss, 4);
        dp += __shfl_xor(dp, 1); dp += __shfl_xor(dp, 2); dp += __shfl_xor(dp, 4);
        if (o == 0) scL[n] = dp * escale / fmaxf(sqrtf(ss), 1e-8f);
    }
    __syncthreads();
    if (tid < 64) {
        float sc = scL[tid];
        float mx = sc;
#pragma unroll
        for (int o = 32; o; o >>= 1) mx = fmaxf(mx, __shfl_xor(mx, o));
        float e = expf(sc - mx);
        float seL = e;
#pragma unroll
        for (int o = 32; o; o >>= 1) seL += __shfl_xor(seL, o);
        wL[tid] = e / seL;
    }
    __syncthreads();
    {
        int c = tid;
        float s = 0.f;
        for (int n = 0; n < 64; ++n) s = fmaf(wL[n], attL[n * 513 + c], s);
        mv[c] = s;
    }
    __syncthreads();
    for (int k = tid; k < 100; k += 512) {
        const float* wp = w_fc + (size_t)k * 1024;
        float acc = b_fc[k];
        for (int c = 0; c < 512; c += 4) {
            float4 w0 = *(const float4*)&wp[c];
            float4 w1 = *(const float4*)&wp[512 + c];
            acc = fmaf(encL[c], w0.x, acc);     acc = fmaf(encL[c + 1], w0.y, acc);
            acc = fmaf(encL[c + 2], w0.z, acc); acc = fmaf(encL[c + 3], w0.w, acc);
            acc = fmaf(mv[c], w1.x, acc);       acc = fmaf(mv[c + 1], w1.y, acc);
            acc = fmaf(mv[c + 2], w1.z, acc);   acc = fmaf(mv[c + 3], w1.w, acc);
        }
        out[b * 100 + k] = acc;
    }
}

extern "C" void kernel_launch(void* const* d_in, const int* in_sizes, int n_in,
                              void* d_out, int out_size, void* d_ws, size_t ws_size,
                              hipStream_t stream) {
    const float* feat_b = (const float*)d_in[0];
    const float* feat_m = (const float*)d_in[1];
    const float* w1x1   = (const float*)d_in[2];
    const float* gamma  = (const float*)d_in[3];
    const float* beta   = (const float*)d_in[4];
    const float* w1a    = (const float*)d_in[5];
    const float* w1b    = (const float*)d_in[6];
    const float* w2a    = (const float*)d_in[7];
    const float* w2b    = (const float*)d_in[8];
    const float* w_fc   = (const float*)d_in[9];
    const float* b_fc   = (const float*)d_in[10];

    float* ws    = (float*)d_ws;
    float* K1w   = ws;                     // 1728 (pad 1760)
    float* fbp   = ws + 1760;              // 51200
    float* fmp   = fbp + 51200;            // 409600
    float* corr  = fmp + 409600;           // 5120000
    float* g1    = corr + 5120000;         // 5120000
    float* attnm = g1 + 5120000;           // 51200
    float* attm  = attnm + 51200;          // 262144

    hipLaunchKernelGGL(k_proj2, dim3(145), dim3(512), 0, stream,
                       feat_b, feat_m, w1x1, gamma, beta, w1a, w1b, K1w, fbp, fmp);
    hipLaunchKernelGGL(k_corr, dim3(512), dim3(512), 0, stream, fbp, fmp, corr);
    hipLaunchKernelGGL(k_cca, dim3(10, 256, 2), dim3(128), 0, stream,
                       corr, K1w, w2a, g1);
    hipLaunchKernelGGL(k_msoft2, dim3(512), dim3(512), 0, stream, g1, w2b, attnm);
    hipLaunchKernelGGL(k_attmem, dim3(64, 4), dim3(128), 0, stream, attnm, feat_m, attm);
    hipLaunchKernelGGL(k_final, dim3(8), dim3(512), 0, stream,
                       feat_b, attm, w_fc, b_fc, (float*)d_out);
}